// Round 1
// baseline (11145.947 us; speedup 1.0000x reference)
//
#include <hip/hip_runtime.h>
#include <hip/hip_bf16.h>

// PeepholeLSTM: SEQ=512, BATCH=64, IN=512, HS=1024, FORGET_BIAS=0
// out = [hidden_seq (512*64*1024) | c_T (64*1024) | h_T (64*1024)] f32
//
// Plan:
//  prep_w  : W f32 -> WxPT bf16 [4096 n][512 k] (perm cols) + WhP bf16 [64 g][128 kb][64 c][8 e]
//  gemm_x  : XP[t][g][c][r] bf16 = (x @ Wx)   (128x128 tile MFMA GEMM, 137 GFLOP)
//  lstm_seq: persistent 64 WGs, Wh slice in LDS (128KB), c in regs, flag barrier per step.

#define SEQN 512
#define BATCH 64
#define INDIM 512
#define HSZ 1024

typedef __attribute__((ext_vector_type(8))) short s16x8;
typedef __attribute__((ext_vector_type(4))) short s16x4;
typedef __attribute__((ext_vector_type(4))) float f32x4;

__device__ __forceinline__ short f2bf(float f) {
  __hip_bfloat16 b = __float2bfloat16(f);
  short s;
  __builtin_memcpy(&s, &b, 2);
  return s;
}
__device__ __forceinline__ float bf2f(short s) {
  unsigned u = ((unsigned)(unsigned short)s) << 16;
  float f;
  __builtin_memcpy(&f, &u, 4);
  return f;
}
__device__ __forceinline__ float sigf(float x) { return 1.f / (1.f + __expf(-x)); }
__device__ __forceinline__ float tanh_fast(float x) { return 2.f / (1.f + __expf(-2.f * x)) - 1.f; }

// ---------------------------------------------------------------------------
// prep_w: one thread per W element (coalesced reads).
// col = gate*1024 + g*16 + off  ->  permuted n = g*64 + gate*16 + off
__global__ __launch_bounds__(256) void prep_w(const float* __restrict__ W,
                                              short* __restrict__ WxPT,
                                              short* __restrict__ WhP) {
  int idx = blockIdx.x * 256 + threadIdx.x;
  if (idx >= 1536 * 4096) return;
  int k = idx >> 12, col = idx & 4095;
  short b = f2bf(W[idx]);
  int gate = col >> 10, rem = col & 1023, g = rem >> 4, off = rem & 15;
  int c = gate * 16 + off;
  if (k < 512) {
    int n = g * 64 + c;
    WxPT[(size_t)n * 512 + k] = b;
  } else {
    int kh = k - 512;
    WhP[(size_t)(((g * 128 + (kh >> 3)) * 64 + c) << 3) + (kh & 7)] = b;
  }
}

// ---------------------------------------------------------------------------
// gemm_x: M=32768 (t*64+b), N=4096 (perm cols), K=512. BM=BN=128, BK=32.
// 4 waves, each 64x64 quadrant (4x4 MFMA 16x16x32 tiles).
// Output XP[t][g][c 64][r 64] bf16 where t=m>>6, r=m&63, g=n>>6, c=n&63.
__global__ __launch_bounds__(256) void gemm_x(const float* __restrict__ x,
                                              const short* __restrict__ WxPT,
                                              short* __restrict__ XP) {
  __shared__ short As[4096];  // [4 kb][128 row][8] bf16 = 8KB
  __shared__ short Bs[4096];  // [4 kb][128 col][8]
  int tid = threadIdx.x;
  int w = tid >> 6, l = tid & 63;
  int mt = blockIdx.x >> 5, nt = blockIdx.x & 31;
  int m0 = mt * 128, n0 = nt * 128;
  f32x4 acc[4][4];
#pragma unroll
  for (int a = 0; a < 4; ++a)
#pragma unroll
    for (int b = 0; b < 4; ++b) acc[a][b] = (f32x4){0.f, 0.f, 0.f, 0.f};

  for (int ks = 0; ks < 16; ++ks) {
    int k0 = ks * 32;
#pragma unroll
    for (int it = 0; it < 2; ++it) {
      int cchunk = it * 256 + tid;           // 512 chunks of 16B
      int kb = cchunk >> 7, rc = cchunk & 127;
      const float4* ap = reinterpret_cast<const float4*>(x + (size_t)(m0 + rc) * 512 + k0 + kb * 8);
      float4 fa = ap[0], fb = ap[1];
      s16x8 av;
      av[0] = f2bf(fa.x); av[1] = f2bf(fa.y); av[2] = f2bf(fa.z); av[3] = f2bf(fa.w);
      av[4] = f2bf(fb.x); av[5] = f2bf(fb.y); av[6] = f2bf(fb.z); av[7] = f2bf(fb.w);
      s16x8 bv = *reinterpret_cast<const s16x8*>(WxPT + (size_t)(n0 + rc) * 512 + k0 + kb * 8);
      reinterpret_cast<s16x8*>(As)[cchunk] = av;
      reinterpret_cast<s16x8*>(Bs)[cchunk] = bv;
    }
    __syncthreads();
    s16x8 af[4], bfr[4];
#pragma unroll
    for (int tm = 0; tm < 4; ++tm)
      af[tm] = reinterpret_cast<s16x8*>(As)[(l >> 4) * 128 + (w >> 1) * 64 + tm * 16 + (l & 15)];
#pragma unroll
    for (int tn = 0; tn < 4; ++tn)
      bfr[tn] = reinterpret_cast<s16x8*>(Bs)[(l >> 4) * 128 + (w & 1) * 64 + tn * 16 + (l & 15)];
#pragma unroll
    for (int tm = 0; tm < 4; ++tm)
#pragma unroll
      for (int tn = 0; tn < 4; ++tn)
        acc[tm][tn] = __builtin_amdgcn_mfma_f32_16x16x32_bf16(af[tm], bfr[tn], acc[tm][tn], 0, 0, 0);
    __syncthreads();
  }
  // epilogue: C/D layout col=lane&15, row=(lane>>4)*4+reg
#pragma unroll
  for (int tm = 0; tm < 4; ++tm)
#pragma unroll
    for (int tn = 0; tn < 4; ++tn)
#pragma unroll
      for (int r = 0; r < 4; ++r) {
        int m = m0 + (w >> 1) * 64 + tm * 16 + (l >> 4) * 4 + r;
        int n = n0 + (w & 1) * 64 + tn * 16 + (l & 15);
        XP[(size_t)(m >> 6) * 262144 + (size_t)(n >> 6) * 4096 + (n & 63) * 64 + (m & 63)] =
            f2bf(acc[tm][tn][r]);
      }
}

// ---------------------------------------------------------------------------
// lstm_seq: 64 persistent WGs x 256 threads. WG g owns h-cols [16g,16g+16).
// Wh slice [128 kb][64 c][8] bf16 = 128KB in LDS. Wave w owns batch rows [16w,16w+16).
// acc tile ct = gate ct (cols ct*16+(l&15)). c-state in regs (4 rows x 1 col per lane).
__global__ __launch_bounds__(256) void lstm_seq(const short* __restrict__ XP,
                                                const short* __restrict__ WhP,
                                                const float* __restrict__ bias,
                                                const float* __restrict__ peep_i,
                                                const float* __restrict__ peep_f,
                                                const float* __restrict__ peep_o,
                                                short* __restrict__ hbuf,
                                                float* __restrict__ out,
                                                unsigned* __restrict__ flags) {
  __shared__ short WhS[65536];  // 128KB
  int g = blockIdx.x;
  int tid = threadIdx.x, w = tid >> 6, l = tid & 63;
  const short* wsrc = WhP + (size_t)g * 65536;
#pragma unroll 4
  for (int it = 0; it < 32; ++it) {
    int cchunk = it * 256 + tid;
    reinterpret_cast<s16x8*>(WhS)[cchunk] = *reinterpret_cast<const s16x8*>(wsrc + cchunk * 8);
  }
  int hcol = g * 16 + (l & 15);
  float bi = bias[hcol], bj = bias[1024 + hcol], bff = bias[2048 + hcol], bo = bias[3072 + hcol];
  float ppi = peep_i[hcol], ppf = peep_f[hcol], ppo = peep_o[hcol];
  float cr[4] = {0.f, 0.f, 0.f, 0.f};
  int rbase = w * 16 + (l >> 4) * 4;
  __syncthreads();

  for (int t = 0; t < SEQN; ++t) {
    // prefetch this step's x-projection (independent of h -> hides under GEMM)
    const short* xpb = XP + ((size_t)t * 64 + g) * 4096;
    s16x4 xv0 = *reinterpret_cast<const s16x4*>(xpb + (0 * 16 + (l & 15)) * 64 + rbase);
    s16x4 xv1 = *reinterpret_cast<const s16x4*>(xpb + (1 * 16 + (l & 15)) * 64 + rbase);
    s16x4 xv2 = *reinterpret_cast<const s16x4*>(xpb + (2 * 16 + (l & 15)) * 64 + rbase);
    s16x4 xv3 = *reinterpret_cast<const s16x4*>(xpb + (3 * 16 + (l & 15)) * 64 + rbase);

    f32x4 acc0 = {0.f, 0.f, 0.f, 0.f}, acc1 = {0.f, 0.f, 0.f, 0.f};
    f32x4 acc2 = {0.f, 0.f, 0.f, 0.f}, acc3 = {0.f, 0.f, 0.f, 0.f};
    if (t > 0) {
      const short* hp = hbuf + (size_t)(t & 1) * 65536;
      const short* arow = hp + (size_t)(w * 16 + (l & 15)) * 1024 + (l >> 4) * 8;
#pragma unroll 4
      for (int kk = 0; kk < 32; ++kk) {
        s16x8 a = *reinterpret_cast<const s16x8*>(arow + kk * 32);
        int kbl = (kk * 4 + (l >> 4)) * 64 + (l & 15);
        s16x8 b0 = reinterpret_cast<s16x8*>(WhS)[kbl];
        s16x8 b1 = reinterpret_cast<s16x8*>(WhS)[kbl + 16];
        s16x8 b2 = reinterpret_cast<s16x8*>(WhS)[kbl + 32];
        s16x8 b3 = reinterpret_cast<s16x8*>(WhS)[kbl + 48];
        acc0 = __builtin_amdgcn_mfma_f32_16x16x32_bf16(a, b0, acc0, 0, 0, 0);
        acc1 = __builtin_amdgcn_mfma_f32_16x16x32_bf16(a, b1, acc1, 0, 0, 0);
        acc2 = __builtin_amdgcn_mfma_f32_16x16x32_bf16(a, b2, acc2, 0, 0, 0);
        acc3 = __builtin_amdgcn_mfma_f32_16x16x32_bf16(a, b3, acc3, 0, 0, 0);
      }
    }
    short* hnext = hbuf + (size_t)((t + 1) & 1) * 65536;
#pragma unroll
    for (int r = 0; r < 4; ++r) {
      int row = rbase + r;
      float cold = cr[r];
      float gi = acc0[r] + bf2f(xv0[r]) + bi;
      float gj = acc1[r] + bf2f(xv1[r]) + bj;
      float gf = acc2[r] + bf2f(xv2[r]) + bff;
      float go = acc3[r] + bf2f(xv3[r]) + bo;
      float it_g = sigf(gi + cold * ppi);
      float ft = sigf(gf + cold * ppf);
      float cn = ft * cold + it_g * tanh_fast(gj);
      float ot = sigf(go + cn * ppo);
      float h = ot * tanh_fast(cn);
      cr[r] = cn;
      out[(size_t)t * 65536 + (size_t)row * 1024 + hcol] = h;
      hnext[(size_t)row * 1024 + hcol] = f2bf(h);
      if (t == SEQN - 1) {
        out[(size_t)33554432 + (size_t)row * 1024 + hcol] = cn;       // c_T
        out[(size_t)33619968 + (size_t)row * 1024 + hcol] = h;        // h_T
      }
    }
    // --- inter-WG barrier: release own flag, wave0 polls all 64 flags ---
    __threadfence();
    __syncthreads();
    if (tid == 0)
      __hip_atomic_store(&flags[g], (unsigned)(t + 1), __ATOMIC_RELEASE, __HIP_MEMORY_SCOPE_AGENT);
    if (tid < 64) {
      int guard = 0;
      while (true) {
        unsigned v = __hip_atomic_load(&flags[tid], __ATOMIC_ACQUIRE, __HIP_MEMORY_SCOPE_AGENT);
        if (__all((int)(v > (unsigned)t))) break;
        if (++guard > (1 << 22)) break;  // safety: fail loud (wrong data), never hang
        __builtin_amdgcn_s_sleep(2);
      }
    }
    __syncthreads();
    __threadfence();
  }
}

// ---------------------------------------------------------------------------
extern "C" void kernel_launch(void* const* d_in, const int* in_sizes, int n_in,
                              void* d_out, int out_size, void* d_ws, size_t ws_size,
                              hipStream_t stream) {
  const float* x      = (const float*)d_in[0];
  const float* W      = (const float*)d_in[1];
  const float* bias   = (const float*)d_in[2];
  const float* peep_i = (const float*)d_in[3];
  const float* peep_f = (const float*)d_in[4];
  const float* peep_o = (const float*)d_in[5];
  char* ws = (char*)d_ws;
  // workspace layout (bytes):
  short* XP    = (short*)(ws);                    // 268435456  bf16 gate pre-acts
  short* WxPT  = (short*)(ws + 268435456ull);     //   4194304
  short* WhP   = (short*)(ws + 272629760ull);     //   8388608
  short* hbuf  = (short*)(ws + 281018368ull);     //    262144  (double-buffered h, bf16)
  unsigned* flags = (unsigned*)(ws + 281280512ull);  // 256
  hipMemsetAsync(flags, 0, 256, stream);
  prep_w<<<24576, 256, 0, stream>>>(W, WxPT, WhP);
  gemm_x<<<8192, 256, 0, stream>>>(x, WxPT, XP);
  lstm_seq<<<64, 256, 0, stream>>>(XP, WhP, bias, peep_i, peep_f, peep_o, hbuf,
                                   (float*)d_out, flags);
}

// Round 3
// 6557.896 us; speedup vs baseline: 1.6996x; 1.6996x over previous
//
#include <hip/hip_runtime.h>
#include <hip/hip_bf16.h>

// PeepholeLSTM: SEQ=512, BATCH=64, IN=512, HS=1024, FORGET_BIAS=0
// out = [hidden_seq (512*64*1024) | c_T (64*1024) | h_T (64*1024)] f32
//
//  prep_w  : W f32 -> WxPT bf16 [4096 n][512 k] (perm cols) + WhP bf16 [64 g][128 kb][64 c][8 e]
//  gemm_x  : XP[t][g][m][c] bf16 = (x @ Wx)   (128x128 tile MFMA GEMM)
//  lstm_seq: persistent 64 WGs, Wh slice in LDS (128KB), c in regs.
//    Swapped MFMA (D = Wh·h^T): lane owns 4 consecutive hidden cols for 1 batch row ->
//    h store = ONE u64 atomic-exchange (executes at LLC), h load = u64 atomic loads (LLC),
//    out = float4 nt store. No fences (round-1 threadfence = full L2 wb = 20us/step),
//    no inline asm, no sub-word atomics (round-2 crash suspects).

#define SEQN 512
#define BATCH 64
#define INDIM 512
#define HSZ 1024

typedef __attribute__((ext_vector_type(8))) short s16x8;
typedef __attribute__((ext_vector_type(4))) short s16x4;
typedef __attribute__((ext_vector_type(4))) float f32x4;

__device__ __forceinline__ short f2bf(float f) {
  __hip_bfloat16 b = __float2bfloat16(f);
  short s;
  __builtin_memcpy(&s, &b, 2);
  return s;
}
__device__ __forceinline__ float bf2f(short s) {
  unsigned u = ((unsigned)(unsigned short)s) << 16;
  float f;
  __builtin_memcpy(&f, &u, 4);
  return f;
}
__device__ __forceinline__ float sigf(float x) { return 1.f / (1.f + __expf(-x)); }
__device__ __forceinline__ float tanh_fast(float x) { return 2.f / (1.f + __expf(-2.f * x)) - 1.f; }

// ---------------------------------------------------------------------------
// prep_w: col = gate*1024 + g*16 + off  ->  permuted n = g*64 + gate*16 + off
__global__ __launch_bounds__(256) void prep_w(const float* __restrict__ W,
                                              short* __restrict__ WxPT,
                                              short* __restrict__ WhP) {
  int idx = blockIdx.x * 256 + threadIdx.x;
  if (idx >= 1536 * 4096) return;
  int k = idx >> 12, col = idx & 4095;
  short b = f2bf(W[idx]);
  int gate = col >> 10, rem = col & 1023, g = rem >> 4, off = rem & 15;
  int c = gate * 16 + off;
  if (k < 512) {
    int n = g * 64 + c;
    WxPT[(size_t)n * 512 + k] = b;
  } else {
    int kh = k - 512;
    WhP[(size_t)(((g * 128 + (kh >> 3)) * 64 + c) << 3) + (kh & 7)] = b;
  }
}

// ---------------------------------------------------------------------------
// gemm_x: M=32768 (t*64+b), N=4096 (perm cols), K=512. BM=BN=128, BK=32.
// Output XP[t][g][m 64][c 64] bf16 (m=batch fast-ish, c contiguous).
__global__ __launch_bounds__(256) void gemm_x(const float* __restrict__ x,
                                              const short* __restrict__ WxPT,
                                              short* __restrict__ XP) {
  __shared__ short As[4096];
  __shared__ short Bs[4096];
  int tid = threadIdx.x;
  int w = tid >> 6, l = tid & 63;
  int mt = blockIdx.x >> 5, nt = blockIdx.x & 31;
  int m0 = mt * 128, n0 = nt * 128;
  f32x4 acc[4][4];
#pragma unroll
  for (int a = 0; a < 4; ++a)
#pragma unroll
    for (int b = 0; b < 4; ++b) acc[a][b] = (f32x4){0.f, 0.f, 0.f, 0.f};

  for (int ks = 0; ks < 16; ++ks) {
    int k0 = ks * 32;
#pragma unroll
    for (int it = 0; it < 2; ++it) {
      int cchunk = it * 256 + tid;  // 512 chunks of 16B
      int kb = cchunk >> 7, rc = cchunk & 127;
      const float4* ap = reinterpret_cast<const float4*>(x + (size_t)(m0 + rc) * 512 + k0 + kb * 8);
      float4 fa = ap[0], fb = ap[1];
      s16x8 av;
      av[0] = f2bf(fa.x); av[1] = f2bf(fa.y); av[2] = f2bf(fa.z); av[3] = f2bf(fa.w);
      av[4] = f2bf(fb.x); av[5] = f2bf(fb.y); av[6] = f2bf(fb.z); av[7] = f2bf(fb.w);
      s16x8 bv = *reinterpret_cast<const s16x8*>(WxPT + (size_t)(n0 + rc) * 512 + k0 + kb * 8);
      reinterpret_cast<s16x8*>(As)[cchunk] = av;
      reinterpret_cast<s16x8*>(Bs)[cchunk] = bv;
    }
    __syncthreads();
    s16x8 af[4], bfr[4];
#pragma unroll
    for (int tm = 0; tm < 4; ++tm)
      af[tm] = reinterpret_cast<s16x8*>(As)[(l >> 4) * 128 + (w >> 1) * 64 + tm * 16 + (l & 15)];
#pragma unroll
    for (int tn = 0; tn < 4; ++tn)
      bfr[tn] = reinterpret_cast<s16x8*>(Bs)[(l >> 4) * 128 + (w & 1) * 64 + tn * 16 + (l & 15)];
#pragma unroll
    for (int tm = 0; tm < 4; ++tm)
#pragma unroll
      for (int tn = 0; tn < 4; ++tn)
        acc[tm][tn] = __builtin_amdgcn_mfma_f32_16x16x32_bf16(af[tm], bfr[tn], acc[tm][tn], 0, 0, 0);
    __syncthreads();
  }
#pragma unroll
  for (int tm = 0; tm < 4; ++tm)
#pragma unroll
    for (int tn = 0; tn < 4; ++tn)
#pragma unroll
      for (int r = 0; r < 4; ++r) {
        int m = m0 + (w >> 1) * 64 + tm * 16 + (l >> 4) * 4 + r;
        int n = n0 + (w & 1) * 64 + tn * 16 + (l & 15);
        XP[(size_t)(m >> 6) * 262144 + (size_t)(n >> 6) * 4096 + (m & 63) * 64 + (n & 63)] =
            f2bf(acc[tm][tn][r]);
      }
}

// ---------------------------------------------------------------------------
// lstm_seq: 64 WGs x 256. WG g owns perm-cols [64g,64g+64) = hidden [16g,16g+16) x 4 gates.
// Wave w owns batch rows [16w,16w+16). Lane l: batch m = w*16+(l&15),
// hidden cols hcol0..hcol0+3 with hcol0 = g*16 + (l>>4)*4.
// D = A(Wh frag from LDS) x B(h frag from LLC): D[i=gate-col][j=batch].
__global__ __launch_bounds__(256, 1) void lstm_seq(const short* __restrict__ XP,
                                                   const short* __restrict__ WhP,
                                                   const float* __restrict__ bias,
                                                   const float* __restrict__ peep_i,
                                                   const float* __restrict__ peep_f,
                                                   const float* __restrict__ peep_o,
                                                   short* hbuf,
                                                   float* __restrict__ out,
                                                   unsigned* flags) {
  __shared__ short WhS[65536];  // 128KB
  int g = blockIdx.x;
  int tid = threadIdx.x, w = tid >> 6, l = tid & 63;
  const short* wsrc = WhP + (size_t)g * 65536;
#pragma unroll 4
  for (int it = 0; it < 32; ++it) {
    int cchunk = it * 256 + tid;
    reinterpret_cast<s16x8*>(WhS)[cchunk] = *reinterpret_cast<const s16x8*>(wsrc + cchunk * 8);
  }
  int m = w * 16 + (l & 15);
  int hcol0 = g * 16 + ((l >> 4) << 2);
  f32x4 bi4 = *reinterpret_cast<const f32x4*>(bias + hcol0);
  f32x4 bj4 = *reinterpret_cast<const f32x4*>(bias + 1024 + hcol0);
  f32x4 bf4 = *reinterpret_cast<const f32x4*>(bias + 2048 + hcol0);
  f32x4 bo4 = *reinterpret_cast<const f32x4*>(bias + 3072 + hcol0);
  f32x4 pi4 = *reinterpret_cast<const f32x4*>(peep_i + hcol0);
  f32x4 pf4 = *reinterpret_cast<const f32x4*>(peep_f + hcol0);
  f32x4 po4 = *reinterpret_cast<const f32x4*>(peep_o + hcol0);
  float cr[4] = {0.f, 0.f, 0.f, 0.f};
  __syncthreads();

  for (int t = 0; t < SEQN; ++t) {
    // x-projection: 4 x 8B plain loads (XP written by prior kernel; normal caching ok)
    const short* xpb = XP + ((size_t)t * 64 + g) * 4096 + m * 64 + ((l >> 4) << 2);
    s16x4 xg0 = *reinterpret_cast<const s16x4*>(xpb);
    s16x4 xg1 = *reinterpret_cast<const s16x4*>(xpb + 16);
    s16x4 xg2 = *reinterpret_cast<const s16x4*>(xpb + 32);
    s16x4 xg3 = *reinterpret_cast<const s16x4*>(xpb + 48);

    f32x4 acc0 = {0.f, 0.f, 0.f, 0.f}, acc1 = {0.f, 0.f, 0.f, 0.f};
    f32x4 acc2 = {0.f, 0.f, 0.f, 0.f}, acc3 = {0.f, 0.f, 0.f, 0.f};
    if (t > 0) {
      // wait for all WGs to have published step t-1 h (flag = t) at the LLC
      if (tid < 64) {
        int guard = 0;
        unsigned v;
        do {
          v = __hip_atomic_load(&flags[tid], __ATOMIC_RELAXED, __HIP_MEMORY_SCOPE_AGENT);
        } while (!__all((int)(v >= (unsigned)t)) && ++guard < (1 << 16));
      }
      __syncthreads();
      // load the wave's h panel (16 rows x 1024 cols bf16) as u64 atomic loads (LLC-coherent)
      unsigned long long hreg[64];
      unsigned long long* hq =
          reinterpret_cast<unsigned long long*>(hbuf + (size_t)(t & 1) * 65536);
      int qbase = m * 256 + ((l >> 4) << 1);
#pragma unroll
      for (int kk = 0; kk < 32; ++kk) {
        hreg[2 * kk] = __hip_atomic_load(hq + qbase + kk * 8, __ATOMIC_RELAXED,
                                         __HIP_MEMORY_SCOPE_AGENT);
        hreg[2 * kk + 1] = __hip_atomic_load(hq + qbase + kk * 8 + 1, __ATOMIC_RELAXED,
                                             __HIP_MEMORY_SCOPE_AGENT);
      }
#pragma unroll
      for (int kk = 0; kk < 32; ++kk) {
        union { unsigned long long q[2]; s16x8 v; } hu;
        hu.q[0] = hreg[2 * kk];
        hu.q[1] = hreg[2 * kk + 1];
        int kbl = (kk * 4 + (l >> 4)) * 64 + (l & 15);
        s16x8 a0 = reinterpret_cast<s16x8*>(WhS)[kbl];
        s16x8 a1 = reinterpret_cast<s16x8*>(WhS)[kbl + 16];
        s16x8 a2 = reinterpret_cast<s16x8*>(WhS)[kbl + 32];
        s16x8 a3 = reinterpret_cast<s16x8*>(WhS)[kbl + 48];
        acc0 = __builtin_amdgcn_mfma_f32_16x16x32_bf16(a0, hu.v, acc0, 0, 0, 0);
        acc1 = __builtin_amdgcn_mfma_f32_16x16x32_bf16(a1, hu.v, acc1, 0, 0, 0);
        acc2 = __builtin_amdgcn_mfma_f32_16x16x32_bf16(a2, hu.v, acc2, 0, 0, 0);
        acc3 = __builtin_amdgcn_mfma_f32_16x16x32_bf16(a3, hu.v, acc3, 0, 0, 0);
      }
    }
    // elementwise: lane has gates i/j/f/o (acc0..3)[r] for hidden col hcol0+r, batch m
    union { unsigned long long q; short s[4]; } hpk;
    f32x4 hv, cv;
#pragma unroll
    for (int r = 0; r < 4; ++r) {
      float cold = cr[r];
      float gi = acc0[r] + bf2f(xg0[r]) + bi4[r];
      float gj = acc1[r] + bf2f(xg1[r]) + bj4[r];
      float gf = acc2[r] + bf2f(xg2[r]) + bf4[r];
      float go = acc3[r] + bf2f(xg3[r]) + bo4[r];
      float it_g = sigf(gi + cold * pi4[r]);
      float ft = sigf(gf + cold * pf4[r]);
      float cn = ft * cold + it_g * tanh_fast(gj);
      float ot = sigf(go + cn * po4[r]);
      float h = ot * tanh_fast(cn);
      cr[r] = cn;
      hpk.s[r] = f2bf(h);
      hv[r] = h;
      cv[r] = cn;
    }
    // publish h for step t+1 at the LLC (atomic exchange executes at coherence point)
    unsigned long long* hnq =
        reinterpret_cast<unsigned long long*>(hbuf + (size_t)((t + 1) & 1) * 65536);
    (void)__hip_atomic_exchange(hnq + m * 256 + (hcol0 >> 2), hpk.q, __ATOMIC_RELAXED,
                                __HIP_MEMORY_SCOPE_AGENT);
    __builtin_nontemporal_store(hv, reinterpret_cast<f32x4*>(out + (size_t)t * 65536 +
                                                             (size_t)m * 1024 + hcol0));
    if (t == SEQN - 1) {
      *reinterpret_cast<f32x4*>(out + 33554432ull + (size_t)m * 1024 + hcol0) = cv;  // c_T
      *reinterpret_cast<f32x4*>(out + 33619968ull + (size_t)m * 1024 + hcol0) = hv;  // h_T
    }
    // __syncthreads drains each wave's tracked vmem (incl. exchanges) before barrier
    __syncthreads();
    if (tid == 0)
      (void)__hip_atomic_exchange(&flags[g], (unsigned)(t + 1), __ATOMIC_RELAXED,
                                  __HIP_MEMORY_SCOPE_AGENT);
  }
}

// ---------------------------------------------------------------------------
extern "C" void kernel_launch(void* const* d_in, const int* in_sizes, int n_in,
                              void* d_out, int out_size, void* d_ws, size_t ws_size,
                              hipStream_t stream) {
  const float* x      = (const float*)d_in[0];
  const float* W      = (const float*)d_in[1];
  const float* bias   = (const float*)d_in[2];
  const float* peep_i = (const float*)d_in[3];
  const float* peep_f = (const float*)d_in[4];
  const float* peep_o = (const float*)d_in[5];
  char* ws = (char*)d_ws;
  short* XP    = (short*)(ws);                       // 268435456  bf16 gate pre-acts
  short* WxPT  = (short*)(ws + 268435456ull);        //   4194304
  short* WhP   = (short*)(ws + 272629760ull);        //   8388608
  short* hbuf  = (short*)(ws + 281018368ull);        //    262144  (double-buffered h, bf16)
  unsigned* flags = (unsigned*)(ws + 281280512ull);  //       256
  hipMemsetAsync(flags, 0, 256, stream);
  prep_w<<<24576, 256, 0, stream>>>(W, WxPT, WhP);
  gemm_x<<<8192, 256, 0, stream>>>(x, WxPT, XP);
  lstm_seq<<<64, 256, 0, stream>>>(XP, WhP, bias, peep_i, peep_f, peep_o, hbuf,
                                   (float*)d_out, flags);
}

// Round 4
// 4507.799 us; speedup vs baseline: 2.4726x; 1.4548x over previous
//
#include <hip/hip_runtime.h>
#include <hip/hip_bf16.h>

// PeepholeLSTM: SEQ=512, BATCH=64, IN=512, HS=1024, FORGET_BIAS=0
// out = [hidden_seq (512*64*1024) | c_T (64*1024) | h_T (64*1024)] f32
//
//  prep_w  : W f32 -> WxPT bf16 [4096 n][512 k] (perm cols) + WhP bf16 [64 g][128 kb][64 c][8 e]
//  gemm_x  : XP[t][g][m][c] bf16 = (x @ Wx)   (128x128 tile MFMA GEMM)
//  lstm_seq: persistent 64 WGs. Cross-WG h exchange is FLAGLESS: each u64 carries
//    [tag:32 | 2 cols bf16], stored via agent-scope atomic exchange (executes at LLC),
//    read via agent-scope atomic loads; consumer retries until tag==t. 4-deep buffer
//    rotation prevents overwrite-before-read (max skew = 1 step). No __syncthreads,
//    no flags, no fences in the step loop -> ~2 LLC hops/step instead of ~4-5.

#define SEQN 512
#define BATCH 64
#define INDIM 512
#define HSZ 1024

typedef __attribute__((ext_vector_type(8))) short s16x8;
typedef __attribute__((ext_vector_type(4))) short s16x4;
typedef __attribute__((ext_vector_type(4))) float f32x4;
typedef unsigned long long u64;

__device__ __forceinline__ short f2bf(float f) {
  __hip_bfloat16 b = __float2bfloat16(f);
  short s;
  __builtin_memcpy(&s, &b, 2);
  return s;
}
__device__ __forceinline__ float bf2f(short s) {
  unsigned u = ((unsigned)(unsigned short)s) << 16;
  float f;
  __builtin_memcpy(&f, &u, 4);
  return f;
}
__device__ __forceinline__ float sigf(float x) { return 1.f / (1.f + __expf(-x)); }
__device__ __forceinline__ float tanh_fast(float x) { return 2.f / (1.f + __expf(-2.f * x)) - 1.f; }

// ---------------------------------------------------------------------------
// prep_w: col = gate*1024 + g*16 + off  ->  permuted n = g*64 + gate*16 + off
__global__ __launch_bounds__(256) void prep_w(const float* __restrict__ W,
                                              short* __restrict__ WxPT,
                                              short* __restrict__ WhP) {
  int idx = blockIdx.x * 256 + threadIdx.x;
  if (idx >= 1536 * 4096) return;
  int k = idx >> 12, col = idx & 4095;
  short b = f2bf(W[idx]);
  int gate = col >> 10, rem = col & 1023, g = rem >> 4, off = rem & 15;
  int c = gate * 16 + off;
  if (k < 512) {
    int n = g * 64 + c;
    WxPT[(size_t)n * 512 + k] = b;
  } else {
    int kh = k - 512;
    WhP[(size_t)(((g * 128 + (kh >> 3)) * 64 + c) << 3) + (kh & 7)] = b;
  }
}

// ---------------------------------------------------------------------------
// gemm_x: M=32768 (t*64+b), N=4096 (perm cols), K=512. BM=BN=128, BK=32.
// Output XP[t][g][m 64][c 64] bf16.
__global__ __launch_bounds__(256) void gemm_x(const float* __restrict__ x,
                                              const short* __restrict__ WxPT,
                                              short* __restrict__ XP) {
  __shared__ short As[4096];
  __shared__ short Bs[4096];
  int tid = threadIdx.x;
  int w = tid >> 6, l = tid & 63;
  int mt = blockIdx.x >> 5, nt = blockIdx.x & 31;
  int m0 = mt * 128, n0 = nt * 128;
  f32x4 acc[4][4];
#pragma unroll
  for (int a = 0; a < 4; ++a)
#pragma unroll
    for (int b = 0; b < 4; ++b) acc[a][b] = (f32x4){0.f, 0.f, 0.f, 0.f};

  for (int ks = 0; ks < 16; ++ks) {
    int k0 = ks * 32;
#pragma unroll
    for (int it = 0; it < 2; ++it) {
      int cchunk = it * 256 + tid;  // 512 chunks of 16B
      int kb = cchunk >> 7, rc = cchunk & 127;
      const float4* ap = reinterpret_cast<const float4*>(x + (size_t)(m0 + rc) * 512 + k0 + kb * 8);
      float4 fa = ap[0], fb = ap[1];
      s16x8 av;
      av[0] = f2bf(fa.x); av[1] = f2bf(fa.y); av[2] = f2bf(fa.z); av[3] = f2bf(fa.w);
      av[4] = f2bf(fb.x); av[5] = f2bf(fb.y); av[6] = f2bf(fb.z); av[7] = f2bf(fb.w);
      s16x8 bv = *reinterpret_cast<const s16x8*>(WxPT + (size_t)(n0 + rc) * 512 + k0 + kb * 8);
      reinterpret_cast<s16x8*>(As)[cchunk] = av;
      reinterpret_cast<s16x8*>(Bs)[cchunk] = bv;
    }
    __syncthreads();
    s16x8 af[4], bfr[4];
#pragma unroll
    for (int tm = 0; tm < 4; ++tm)
      af[tm] = reinterpret_cast<s16x8*>(As)[(l >> 4) * 128 + (w >> 1) * 64 + tm * 16 + (l & 15)];
#pragma unroll
    for (int tn = 0; tn < 4; ++tn)
      bfr[tn] = reinterpret_cast<s16x8*>(Bs)[(l >> 4) * 128 + (w & 1) * 64 + tn * 16 + (l & 15)];
#pragma unroll
    for (int tm = 0; tm < 4; ++tm)
#pragma unroll
      for (int tn = 0; tn < 4; ++tn)
        acc[tm][tn] = __builtin_amdgcn_mfma_f32_16x16x32_bf16(af[tm], bfr[tn], acc[tm][tn], 0, 0, 0);
    __syncthreads();
  }
#pragma unroll
  for (int tm = 0; tm < 4; ++tm)
#pragma unroll
    for (int tn = 0; tn < 4; ++tn)
#pragma unroll
      for (int r = 0; r < 4; ++r) {
        int m = m0 + (w >> 1) * 64 + tm * 16 + (l >> 4) * 4 + r;
        int n = n0 + (w & 1) * 64 + tn * 16 + (l & 15);
        XP[(size_t)(m >> 6) * 262144 + (size_t)(n >> 6) * 4096 + (m & 63) * 64 + (n & 63)] =
            f2bf(acc[tm][tn][r]);
      }
}

// ---------------------------------------------------------------------------
// lstm_seq: 64 WGs x 256. WG g owns hidden [16g,16g+16) (perm-cols [64g,64g+64)).
// Wave w owns batch rows [16w,16w+16); lane l: m = w*16+(l&15), hcol0 = g*16+(l>>4)*4.
// Tagged h buffer: tagq[t&3][pair 0..511][m 0..63] u64 = (tag=t)<<32 | bf16[2p+1]<<16 | bf16[2p].
// Consumer at step t expects tag == t on every u64 it reads (h_{t-1}).
__global__ __launch_bounds__(256, 1) void lstm_seq(const short* __restrict__ XP,
                                                   const short* __restrict__ WhP,
                                                   const float* __restrict__ bias,
                                                   const float* __restrict__ peep_i,
                                                   const float* __restrict__ peep_f,
                                                   const float* __restrict__ peep_o,
                                                   u64* tagq,
                                                   float* __restrict__ out) {
  __shared__ short WhS[65536];  // 128KB
  int g = blockIdx.x;
  int tid = threadIdx.x, w = tid >> 6, l = tid & 63;
  const short* wsrc = WhP + (size_t)g * 65536;
#pragma unroll 4
  for (int it = 0; it < 32; ++it) {
    int cchunk = it * 256 + tid;
    reinterpret_cast<s16x8*>(WhS)[cchunk] = *reinterpret_cast<const s16x8*>(wsrc + cchunk * 8);
  }
  int m = w * 16 + (l & 15);
  int q4 = l >> 4;
  int hcol0 = g * 16 + (q4 << 2);
  f32x4 bi4 = *reinterpret_cast<const f32x4*>(bias + hcol0);
  f32x4 bj4 = *reinterpret_cast<const f32x4*>(bias + 1024 + hcol0);
  f32x4 bf4 = *reinterpret_cast<const f32x4*>(bias + 2048 + hcol0);
  f32x4 bo4 = *reinterpret_cast<const f32x4*>(bias + 3072 + hcol0);
  f32x4 pi4 = *reinterpret_cast<const f32x4*>(peep_i + hcol0);
  f32x4 pf4 = *reinterpret_cast<const f32x4*>(peep_f + hcol0);
  f32x4 po4 = *reinterpret_cast<const f32x4*>(peep_o + hcol0);
  float cr[4] = {0.f, 0.f, 0.f, 0.f};
  int rdoff = q4 * 256 + m;  // per-lane base inside a step-buffer (u64 units)
  s16x8* WhS16 = reinterpret_cast<s16x8*>(WhS);
  __syncthreads();

// load group G (8 kk-blocks): 32 u64 per lane; pair P = 16kk + q4*4 + j, addr = P*64+m
#define LOADG(BANK, G)                                                                   \
  {                                                                                      \
    _Pragma("unroll") for (int i = 0; i < 32; ++i) {                                     \
      BANK[i] = __hip_atomic_load(rdq + (G) * 8192 + (i >> 2) * 1024 + (i & 3) * 64 +    \
                                      rdoff,                                             \
                                  __ATOMIC_RELAXED, __HIP_MEMORY_SCOPE_AGENT);           \
    }                                                                                    \
  }

#define CHECKG(BANK, G)                                                                  \
  {                                                                                      \
    int guard = 0;                                                                       \
    while (true) {                                                                       \
      bool ok = true;                                                                    \
      _Pragma("unroll") for (int i = 0; i < 32; ++i) ok &=                               \
          ((unsigned)(BANK[i] >> 32) == (unsigned)t);                                    \
      if (__all((int)ok)) break;                                                         \
      if (++guard > (1 << 14)) break; /* fail loud, never hang */                        \
      LOADG(BANK, G);                                                                    \
    }                                                                                    \
  }

#define MFMAG(BANK, G)                                                                   \
  {                                                                                      \
    _Pragma("unroll") for (int kk2 = 0; kk2 < 8; ++kk2) {                                \
      int kk = (G) * 8 + kk2;                                                            \
      union { unsigned u[4]; s16x8 v; } bu;                                              \
      bu.u[0] = (unsigned)BANK[kk2 * 4 + 0];                                             \
      bu.u[1] = (unsigned)BANK[kk2 * 4 + 1];                                             \
      bu.u[2] = (unsigned)BANK[kk2 * 4 + 2];                                             \
      bu.u[3] = (unsigned)BANK[kk2 * 4 + 3];                                             \
      int kbl = (kk * 4 + q4) * 64 + (l & 15);                                           \
      s16x8 a0 = WhS16[kbl];                                                             \
      s16x8 a1 = WhS16[kbl + 16];                                                        \
      s16x8 a2 = WhS16[kbl + 32];                                                        \
      s16x8 a3 = WhS16[kbl + 48];                                                        \
      acc0 = __builtin_amdgcn_mfma_f32_16x16x32_bf16(a0, bu.v, acc0, 0, 0, 0);           \
      acc1 = __builtin_amdgcn_mfma_f32_16x16x32_bf16(a1, bu.v, acc1, 0, 0, 0);           \
      acc2 = __builtin_amdgcn_mfma_f32_16x16x32_bf16(a2, bu.v, acc2, 0, 0, 0);           \
      acc3 = __builtin_amdgcn_mfma_f32_16x16x32_bf16(a3, bu.v, acc3, 0, 0, 0);           \
    }                                                                                    \
  }

  for (int t = 0; t < SEQN; ++t) {
    // x-projection prefetch (plain loads; inter-kernel coherence via dispatch acq/rel)
    const short* xpb = XP + ((size_t)t * 64 + g) * 4096 + m * 64 + (q4 << 2);
    s16x4 xg0 = *reinterpret_cast<const s16x4*>(xpb);
    s16x4 xg1 = *reinterpret_cast<const s16x4*>(xpb + 16);
    s16x4 xg2 = *reinterpret_cast<const s16x4*>(xpb + 32);
    s16x4 xg3 = *reinterpret_cast<const s16x4*>(xpb + 48);

    f32x4 acc0 = {0.f, 0.f, 0.f, 0.f}, acc1 = {0.f, 0.f, 0.f, 0.f};
    f32x4 acc2 = {0.f, 0.f, 0.f, 0.f}, acc3 = {0.f, 0.f, 0.f, 0.f};
    if (t > 0) {
      const u64* rdq = tagq + (size_t)(t & 3) * 32768;
      u64 hA[32], hB[32];
      LOADG(hA, 0);
      LOADG(hB, 1);
      CHECKG(hA, 0);
      MFMAG(hA, 0);
      LOADG(hA, 2);
      CHECKG(hB, 1);
      MFMAG(hB, 1);
      LOADG(hB, 3);
      CHECKG(hA, 2);
      MFMAG(hA, 2);
      CHECKG(hB, 3);
      MFMAG(hB, 3);
    }
    // elementwise: lane has gates i/j/f/o (acc0..3)[r] for hidden col hcol0+r, batch m
    f32x4 hv, cv;
    short hs[4];
#pragma unroll
    for (int r = 0; r < 4; ++r) {
      float cold = cr[r];
      float gi = acc0[r] + bf2f(xg0[r]) + bi4[r];
      float gj = acc1[r] + bf2f(xg1[r]) + bj4[r];
      float gf = acc2[r] + bf2f(xg2[r]) + bf4[r];
      float go = acc3[r] + bf2f(xg3[r]) + bo4[r];
      float it_g = sigf(gi + cold * pi4[r]);
      float ft = sigf(gf + cold * pf4[r]);
      float cn = ft * cold + it_g * tanh_fast(gj);
      float ot = sigf(go + cn * po4[r]);
      float h = ot * tanh_fast(cn);
      cr[r] = cn;
      hs[r] = f2bf(h);
      hv[r] = h;
      cv[r] = cn;
    }
    // publish tagged h_t (tag = t+1) into buffer (t+1)&3; exchange executes at LLC
    {
      u64* wrq = tagq + (size_t)((t + 1) & 3) * 32768;
      unsigned lo0 = (unsigned)(unsigned short)hs[0] | ((unsigned)(unsigned short)hs[1] << 16);
      unsigned lo1 = (unsigned)(unsigned short)hs[2] | ((unsigned)(unsigned short)hs[3] << 16);
      u64 q0 = ((u64)(unsigned)(t + 1) << 32) | lo0;
      u64 q1 = ((u64)(unsigned)(t + 1) << 32) | lo1;
      int P0 = hcol0 >> 1;
      (void)__hip_atomic_exchange(wrq + P0 * 64 + m, q0, __ATOMIC_RELAXED,
                                  __HIP_MEMORY_SCOPE_AGENT);
      (void)__hip_atomic_exchange(wrq + (P0 + 1) * 64 + m, q1, __ATOMIC_RELAXED,
                                  __HIP_MEMORY_SCOPE_AGENT);
    }
    __builtin_nontemporal_store(hv, reinterpret_cast<f32x4*>(out + (size_t)t * 65536 +
                                                             (size_t)m * 1024 + hcol0));
    if (t == SEQN - 1) {
      *reinterpret_cast<f32x4*>(out + 33554432ull + (size_t)m * 1024 + hcol0) = cv;  // c_T
      *reinterpret_cast<f32x4*>(out + 33619968ull + (size_t)m * 1024 + hcol0) = hv;  // h_T
    }
  }
#undef LOADG
#undef CHECKG
#undef MFMAG
}

// ---------------------------------------------------------------------------
extern "C" void kernel_launch(void* const* d_in, const int* in_sizes, int n_in,
                              void* d_out, int out_size, void* d_ws, size_t ws_size,
                              hipStream_t stream) {
  const float* x      = (const float*)d_in[0];
  const float* W      = (const float*)d_in[1];
  const float* bias   = (const float*)d_in[2];
  const float* peep_i = (const float*)d_in[3];
  const float* peep_f = (const float*)d_in[4];
  const float* peep_o = (const float*)d_in[5];
  char* ws = (char*)d_ws;
  short* XP   = (short*)(ws);                  // 268435456  bf16 gate pre-acts
  short* WxPT = (short*)(ws + 268435456ull);   //   4194304
  short* WhP  = (short*)(ws + 272629760ull);   //   8388608
  u64* tagq   = (u64*)(ws + 281018368ull);     //   1048576  (4 x 256KB tagged h buffers)
  // zero tags every launch: leftover tags from a previous replay would alias this
  // run's expected tag sequence (deterministic), silently skipping synchronization
  hipMemsetAsync(tagq, 0, 1048576, stream);
  prep_w<<<24576, 256, 0, stream>>>(W, WxPT, WhP);
  gemm_x<<<8192, 256, 0, stream>>>(x, WxPT, XP);
  lstm_seq<<<64, 256, 0, stream>>>(XP, WhP, bias, peep_i, peep_f, peep_o, tagq,
                                   (float*)d_out);
}